// Round 6
// baseline (297.272 us; speedup 1.0000x reference)
//
#include <hip/hip_runtime.h>
#include <math.h>

// Problem constants (fixed by the reference)
#define NN 129
#define FF 262144
#define EE 16384
#define CHUNKS 32
#define CHUNK (FF / CHUNKS)   // 8192 floats per matvec block
#define NMV (NN * CHUNKS)     // 4128 matvec blocks

// Tail: ONE block. 64 edges/thread, loads batched 8-wide for pipelining.
#define EPT_T (EE / 256)      // 64
#define SB 8                  // scan batch (8 x float4 = 32 VGPR, pipelined)
#define NSB (EPT_T / SB)      // 8

// ws layout (doubles)
#define OFF_PARTIAL 0                              // [NMV] = 4128
#define OFF_SORT    (OFF_PARTIAL + NMV)            // 16384 records x 16 B

// Sync: 64 cachelines, stream done-counters (bm & 63). Zero at module load;
// block 0 self-resets at end of every launch (no memset dispatch needed).
#define LSTRIDE 32            // uints per 128-B line
__device__ __align__(128) unsigned g_sync[64 * LSTRIDE];

typedef float vfloat4 __attribute__((ext_vector_type(4)));

__device__ __forceinline__ double agent_ld(const double* p) {
    return __hip_atomic_load(p, __ATOMIC_RELAXED, __HIP_MEMORY_SCOPE_AGENT);
}
__device__ __forceinline__ void agent_st(double* p, double v) {
    __hip_atomic_store(p, v, __ATOMIC_RELAXED, __HIP_MEMORY_SCOPE_AGENT);
}

// Run-length aggregation scan over destination-sorted records.
// MODE 0: weighted degree. MODE 1: layer-1 (nw * xw[r]). MODE 2: layer-2
// (nw * (sh1[r] * w2)). Loads batched SB-wide so the 64 per-thread record
// reads pipeline (round-4's one-per-iteration loads were ~19 us/scan).
// ~1 LDS atomic flush per run boundary (~385 total vs 49K naive).
template<int MODE>
__device__ __forceinline__ void scan_edges(
    const float4* __restrict__ recs, double* agg,
    const double* sdinv, const double* sxw, const double* sh1,
    double w2, int tid)
{
    const int base = tid * EPT_T;
    double a0 = 0.0, a1 = 0.0, a2 = 0.0;
    int cur = -1;
    for (int bt = 0; bt < NSB; ++bt) {
        float4 rb[SB];
#pragma unroll
        for (int i = 0; i < SB; ++i) rb[i] = recs[base + bt * SB + i];
#pragma unroll
        for (int i = 0; i < SB; ++i) {
            const int rc = __float_as_int(rb[i].x);
            const int cl = rc & 255, r = rc >> 8;
            if (cl != cur) {
                if (cur >= 0) {
                    unsafeAtomicAdd(&agg[0 * NN + cur], a0);
                    unsafeAtomicAdd(&agg[1 * NN + cur], a1);
                    unsafeAtomicAdd(&agg[2 * NN + cur], a2);
                }
                cur = cl; a0 = a1 = a2 = 0.0;
            }
            if (MODE == 0) {
                a0 += (double)rb[i].y; a1 += (double)rb[i].z; a2 += (double)rb[i].w;
            } else {
                const double nw0 = sdinv[0 * NN + r] * (double)rb[i].y * sdinv[0 * NN + cl];
                const double nw1 = sdinv[1 * NN + r] * (double)rb[i].z * sdinv[1 * NN + cl];
                const double nw2 = sdinv[2 * NN + r] * (double)rb[i].w * sdinv[2 * NN + cl];
                if (MODE == 1) {
                    const double xwr = sxw[r];
                    a0 += nw0 * xwr; a1 += nw1 * xwr; a2 += nw2 * xwr;
                } else {
                    a0 += nw0 * (sh1[0 * NN + r] * w2);
                    a1 += nw1 * (sh1[1 * NN + r] * w2);
                    a2 += nw2 * (sh1[2 * NN + r] * w2);
                }
            }
        }
    }
    if (cur >= 0) {
        unsafeAtomicAdd(&agg[0 * NN + cur], a0);
        unsafeAtomicAdd(&agg[1 * NN + cur], a1);
        unsafeAtomicAdd(&agg[2 * NN + cur], a2);
    }
}

// ---------------------------------------------------------------------------
// Fused kernel, single-tail-block + batched-scan edition.
//   Block 0         : counting sort + degree + dinv during the stream overlap;
//                     post-stream: xw (batched), 2 scans (batched), finale.
//                     ZERO device barriers — only __syncthreads.
//   Blocks [1,NMV]  : streaming matvec partials (unchanged, proven).
// ---------------------------------------------------------------------------
__global__ __launch_bounds__(256, 6) void k_fused(
    const float* __restrict__ x, const float* __restrict__ W,
    const int* __restrict__ eidx, const float* __restrict__ eattr,
    double* __restrict__ ws,
    const float* __restrict__ b1, const float* __restrict__ W2, const float* __restrict__ b2,
    const float* __restrict__ c1w, const float* __restrict__ c1b,
    const float* __restrict__ c2w, const float* __restrict__ c2b,
    const float* __restrict__ f1W, const float* __restrict__ f1b,
    const float* __restrict__ f2W, const float* __restrict__ f2b,
    const float* __restrict__ f3W, const float* __restrict__ f3b,
    float* __restrict__ out)
{
    const int b = blockIdx.x;
    const int tid = threadIdx.x;
    const int wave = tid >> 6, lane = tid & 63;

    // Persistent tail state: sxw[129] | sdinv[3*129] | sh1[3*129]
    __shared__ double P[129 + 387 + 387];
    // Time-aliased scratch (1935 doubles):
    //   scans:  agg[3*NN] @0..387
    //   finale: z0@0(387) z1@387(387) rnk(int)@774 c1o@774(1143)
    //           h2f@1548(387) c2o@0(369) allx@369(363)
    __shared__ double SCR[1935];
    __shared__ int    sbin[NN];               // histogram counts
    __shared__ int    scur[NN];               // scatter cursors
    __shared__ double ws4[4];                 // matvec wave partials
    __shared__ double fcb[38];                // fc1o[32] | fc2o[6]

    if (b != 0) {
        // ---- Streaming matvec partial: one (row, chunk) dot-product block.
        // x non-temporal so the 135 MB stream doesn't evict W (L2-hot, 129x reuse).
        const int bm = b - 1;
        const int r = bm / CHUNKS, ch = bm % CHUNKS;
        const vfloat4* xp = (const vfloat4*)(x + (size_t)r * FF + (size_t)ch * CHUNK);
        const float4*  wp = (const float4*)(W + (size_t)ch * CHUNK);
        double acc0 = 0.0, acc1 = 0.0;
#pragma unroll
        for (int i = 0; i < CHUNK / (256 * 4); ++i) {   // 8 iters
            vfloat4 xv = __builtin_nontemporal_load(xp + tid + i * 256);
            float4  wv = wp[tid + i * 256];
            acc0 += (double)xv[0] * (double)wv.x + (double)xv[1] * (double)wv.y;
            acc1 += (double)xv[2] * (double)wv.z + (double)xv[3] * (double)wv.w;
        }
        double acc = acc0 + acc1;
        for (int off = 32; off > 0; off >>= 1) acc += __shfl_down(acc, off, 64);
        if (lane == 0) ws4[wave] = acc;
        __syncthreads();
        if (tid == 0) {
            const double v = (ws4[0] + ws4[1]) + (ws4[2] + ws4[3]);
            agent_st(&ws[OFF_PARTIAL + bm], v);
            asm volatile("s_waitcnt vmcnt(0)" ::: "memory");  // store before signal
            __hip_atomic_fetch_add(&g_sync[(bm & 63) * LSTRIDE], 1u,
                                   __ATOMIC_RELAXED, __HIP_MEMORY_SCOPE_AGENT);
        }
        return;
    }

    // ======================== tail (single block 0) ========================
    double* sxw   = P;            // [NN]
    double* sdinv = P + 129;      // [3*NN]
    double* sh1   = P + 516;      // [3*NN]
    double* agg   = SCR;          // [3*NN]
    float4* recs  = (float4*)(ws + OFF_SORT);

    // ---------- A: counting sort by destination (overlaps matvec stream) ----
    for (int i = tid; i < NN; i += 256) sbin[i] = 0;
    __syncthreads();
    for (int bt = 0; bt < EPT_T / 8; ++bt) {       // histogram, 8-batched
        int c8[8];
#pragma unroll
        for (int i = 0; i < 8; ++i)
            c8[i] = eidx[EE + (bt * 8 + i) * 256 + tid];
#pragma unroll
        for (int i = 0; i < 8; ++i) atomicAdd(&sbin[c8[i]], 1);
    }
    __syncthreads();
    if (tid == 0) {                                // exclusive prefix -> cursors
        int run = 0;
        for (int j = 0; j < NN; ++j) { scur[j] = run; run += sbin[j]; }
    }
    __syncthreads();
    for (int bt = 0; bt < EPT_T / 4; ++bt) {       // scatter, 4-batched
        int r4[4], c4[4];
        float a4[4][3];
#pragma unroll
        for (int i = 0; i < 4; ++i) {
            const int e = (bt * 4 + i) * 256 + tid;
            r4[i] = eidx[e];
            c4[i] = eidx[EE + e];
            a4[i][0] = eattr[e * 3 + 0];
            a4[i][1] = eattr[e * 3 + 1];
            a4[i][2] = eattr[e * 3 + 2];
        }
#pragma unroll
        for (int i = 0; i < 4; ++i) {
            const int pos = atomicAdd(&scur[c4[i]], 1);
            float4 rec;
            rec.x = __int_as_float((r4[i] << 8) | c4[i]);
            rec.y = a4[i][0]; rec.z = a4[i][1]; rec.w = a4[i][2];
            recs[pos] = rec;
        }
    }
    __threadfence_block();
    __syncthreads();

    // ---------- B: weighted-degree scan + dinv (still overlapping stream) ---
    for (int i = tid; i < 3 * NN; i += 256) agg[i] = 0.0;
    __syncthreads();
    scan_edges<0>(recs, agg, sdinv, sxw, sh1, 0.0, tid);
    __syncthreads();
    for (int v = tid; v < 3 * NN; v += 256) {
        const double d = 1.0 + agg[v];             // +1 self loop
        sdinv[v] = (d > 0.0) ? 1.0 / sqrt(d) : 0.0;
    }
    __syncthreads();

    // ---------- Wait for all matvec partials: 64 lanes on 64 lines ----------
    // 4128 = 64*64 + 32 -> lanes 0..31 expect 65, lanes 32..63 expect 64.
    if (tid < 64) {
        unsigned* c = &g_sync[tid * LSTRIDE];
        const unsigned expct = (tid < 32) ? 65u : 64u;
        while (__hip_atomic_load(c, __ATOMIC_RELAXED, __HIP_MEMORY_SCOPE_AGENT) < expct)
            __builtin_amdgcn_s_sleep(8);
    }
    __syncthreads();

    // ---------- xw row sums (8-batched; same left-to-right order) ----------
    for (int j = tid; j < NN; j += 256) {
        double s = 0.0;
        for (int kk = 0; kk < CHUNKS / 8; ++kk) {
            double v8[8];
#pragma unroll
            for (int u = 0; u < 8; ++u)
                v8[u] = agent_ld(&ws[OFF_PARTIAL + j * CHUNKS + kk * 8 + u]);
#pragma unroll
            for (int u = 0; u < 8; ++u) s += v8[u];
        }
        sxw[j] = s;
    }
    for (int i = tid; i < 3 * NN; i += 256) agg[i] = 0.0;
    __syncthreads();

    // ---------- Layer-1 scan ----------
    scan_edges<1>(recs, agg, sdinv, sxw, sh1, 0.0, tid);
    __syncthreads();

    // ---------- h1 ----------
    const double bb1 = (double)b1[0];
    for (int i = tid; i < 3 * NN; i += 256) {
        const int j = i % NN;
        const double dv = sdinv[i];
        sh1[i] = dv * dv * sxw[j] + bb1 + agg[i];
    }
    __syncthreads();
    for (int i = tid; i < 3 * NN; i += 256) agg[i] = 0.0;
    __syncthreads();

    // ---------- Layer-2 scan ----------
    const double w2 = (double)W2[0];
    scan_edges<2>(recs, agg, sdinv, sxw, sh1, w2, tid);
    __syncthreads();

    // ---------- h2 ----------
    double* h2f = SCR + 1548;              // [3*NN]
    const double bb2 = (double)b2[0];
    for (int i = tid; i < 3 * NN; i += 256) {
        const double dv = sdinv[i];
        h2f[i] = dv * dv * (sh1[i] * w2) + bb2 + agg[i];
    }
    __syncthreads();

    // ---------- Finale (agg dead; SCR re-used) ----------
    double* z0   = SCR;                    // [3*NN]  live: z-fill .. conv1
    double* z1   = SCR + 387;              // [3*NN]  live: z-fill .. conv1
    int*    rnk  = (int*)(SCR + 774);      // [3*NN] ints, live: rank .. z-fill
    double* c1o  = SCR + 774;              // [3*3*127] live: conv1 .. conv2
    double* c2o  = SCR;                    // [3*123] live: conv2 .. pool
    double* allx = SCR + 369;              // [363]   live: pool .. fc1
    double* fc1o = fcb;                    // [32]
    double* fc2o = fcb + 32;               // [6]

    // SortPool: stable argsort of -h2 (descending, ties by index), k = N
    for (int i = tid; i < 3 * NN; i += 256) {
        const int c = i / NN, j = i % NN;
        const double v = h2f[c * NN + j];
        int rk = 0;
        for (int q = 0; q < NN; ++q) {
            const double u = h2f[c * NN + q];
            rk += (u > v) || (u == v && q < j);
        }
        rnk[i] = rk;
    }
    __syncthreads();
    for (int i = tid; i < 3 * NN; i += 256) {
        const int c = i / NN;
        const int rk = rnk[i];
        z0[c * NN + rk] = sh1[i];
        z1[c * NN + rk] = h2f[i];
    }
    __syncthreads();

    // conv1 (in=2,out=3,k=3, VALID) -> 127   (rnk dead; c1o region free)
    for (int i = tid; i < 3 * 3 * 127; i += 256) {
        const int c = i / (3 * 127), rem = i % (3 * 127), o = rem / 127, p = rem % 127;
        double s = (double)c1b[o];
#pragma unroll
        for (int k = 0; k < 3; ++k) {
            s += (double)c1w[(o * 2 + 0) * 3 + k] * z0[c * NN + p + k];
            s += (double)c1w[(o * 2 + 1) * 3 + k] * z1[c * NN + p + k];
        }
        c1o[(c * 3 + o) * 127 + p] = s;
    }
    __syncthreads();

    // pool1 fused into conv2 (identical f64 op order to materialized version)
    for (int i = tid; i < 3 * 123; i += 256) {
        const int c = i / 123, p = i % 123;
        double s = (double)c2b[0];
#pragma unroll
        for (int ic = 0; ic < 3; ++ic)
#pragma unroll
            for (int k = 0; k < 3; ++k) {
                const double* base = c1o + (c * 3 + ic) * 127 + p + k;
                const double m = fmax(base[0], fmax(base[1], base[2]));
                s += (double)c2w[ic * 3 + k] * m;
            }
        c2o[c * 123 + p] = s;
    }
    __syncthreads();
    for (int i = tid; i < 3 * 121; i += 256) {
        const int c = i / 121, p = i % 121;
        allx[c * 121 + p] = fmax(c2o[c * 123 + p],
                            fmax(c2o[c * 123 + p + 1], c2o[c * 123 + p + 2]));
    }
    __syncthreads();

    // fc1: 363 -> 32, ELU (8 lanes per output, aligned subgroups)
    {
        const int j = tid >> 3, t = tid & 7;
        double s = 0.0;
        for (int i = t; i < 363; i += 8) s += allx[i] * (double)f1W[i * 32 + j];
        s += __shfl_down(s, 4, 8);
        s += __shfl_down(s, 2, 8);
        s += __shfl_down(s, 1, 8);
        if (t == 0) {
            s += (double)f1b[j];
            fc1o[j] = (s > 0.0) ? s : expm1(s);
        }
    }
    __syncthreads();
    if (tid < 6) {
        double s = (double)f2b[tid];
        for (int i = 0; i < 32; ++i) s += fc1o[i] * (double)f2W[i * 6 + tid];
        fc2o[tid] = (s > 0.0) ? s : expm1(s);
    }
    __syncthreads();
    if (tid < 2) {
        double s = (double)f3b[tid];
        for (int i = 0; i < 6; ++i) s += fc2o[i] * (double)f3W[i * 2 + tid];
        out[tid] = (float)s;
    }

    // ---- Self-reset sync counters for the next launch (block 0 observed all
    // 4128 arrivals, so no other block touches g_sync after this point).
    __syncthreads();
    if (tid < 64)
        __hip_atomic_store(&g_sync[tid * LSTRIDE], 0u,
                           __ATOMIC_RELAXED, __HIP_MEMORY_SCOPE_AGENT);
}

extern "C" void kernel_launch(void* const* d_in, const int* in_sizes, int n_in,
                              void* d_out, int out_size, void* d_ws, size_t ws_size,
                              hipStream_t stream) {
    const float* x    = (const float*)d_in[0];
    const int*   eidx = (const int*)d_in[1];
    const float* eattr= (const float*)d_in[2];
    const float* g1W  = (const float*)d_in[3];
    const float* g1b  = (const float*)d_in[4];
    const float* g2W  = (const float*)d_in[5];
    const float* g2b  = (const float*)d_in[6];
    const float* c1w  = (const float*)d_in[7];
    const float* c1b  = (const float*)d_in[8];
    const float* c2w  = (const float*)d_in[9];
    const float* c2b  = (const float*)d_in[10];
    const float* f1W  = (const float*)d_in[11];
    const float* f1b  = (const float*)d_in[12];
    const float* f2W  = (const float*)d_in[13];
    const float* f2b  = (const float*)d_in[14];
    const float* f3W  = (const float*)d_in[15];
    const float* f3b  = (const float*)d_in[16];
    float* out = (float*)d_out;
    double* ws = (double*)d_ws;

    // No memset: sync counters live in g_sync (zero at load, self-reset each run).
    k_fused<<<NMV + 1, 256, 0, stream>>>(
        x, g1W, eidx, eattr, ws,
        g1b, g2W, g2b, c1w, c1b, c2w, c2b,
        f1W, f1b, f2W, f2b, f3W, f3b, out);
}

// Round 7
// 256.301 us; speedup vs baseline: 1.1599x; 1.1599x over previous
//
#include <hip/hip_runtime.h>
#include <math.h>

// Problem constants (fixed by the reference)
#define NN 129
#define FF 262144
#define EE 16384
#define CHUNKS 32
#define CHUNK (FF / CHUNKS)   // 8192 floats per matvec block
#define NB 16                 // tail blocks
#define EPB (EE / NB)         // 1024 edges per block
#define EPT (EPB / 256)       // 4 edges per thread
#define NMV (NN * CHUNKS)     // 4128 matvec blocks

// ws layout (doubles) — data only; sync lives in g_sync (device global)
#define OFF_PARTIAL 0                              // [NMV] = 4128
#define OFF_DEGP    (OFF_PARTIAL + NMV)            // [NB*3*NN]
#define OFF_H1P     (OFF_DEGP + NB*3*NN)           // [NB*3*NN]
#define OFF_H2P     (OFF_H1P + NB*3*NN)            // [NB*3*NN]

// Sync: 67 cachelines (128 B apart). 0..63 = stream done-counters (bm & 63);
// 64/65/66 = tail barriers. Zero at module load; block 0 self-resets at end
// of every launch (no memset dispatch).
#define LSTRIDE 32            // uints per 128-B line
__device__ __align__(128) unsigned g_sync[67 * LSTRIDE];

typedef float vfloat4 __attribute__((ext_vector_type(4)));

// ---------------------------------------------------------------------------
// FULLY-RELAXED device barrier for the NB tail blocks.
//
// Round-7 change (the theory under test): rounds 2-6 used ACQ_REL arrival +
// ACQUIRE spin-polls. Agent-scope acquire/release compile to L2 cache
// maintenance ops (invalidate / writeback) — an invalidate PER POLL
// ITERATION on 16 CUs across all 8 XCDs, including during the stream
// overlap window. That evicts the L2-resident W panel the stream reuses
// 129x and forces every post-barrier read to re-miss.
//
// Correctness without acquire/release: all cross-block data moves through
// relaxed AGENT atomics (write-through to the device coherence point; the
// same protocol as the matvec handoff, absmax 0.0 across 5 rounds).
// Producers' stores are complete BEFORE arrival because __syncthreads
// drains vmcnt for every wave (compiler emits s_waitcnt vmcnt(0) before
// s_barrier). Readers use relaxed agent loads that bypass the incoherent
// caches. asm "memory" fences pin compiler-level ordering only (no ISA op).
// ---------------------------------------------------------------------------
__device__ __forceinline__ void gbar(unsigned* line) {
    __syncthreads();
    if (threadIdx.x == 0) {
        asm volatile("" ::: "memory");
        __hip_atomic_fetch_add(line, 1u, __ATOMIC_RELAXED, __HIP_MEMORY_SCOPE_AGENT);
        while (__hip_atomic_load(line, __ATOMIC_RELAXED, __HIP_MEMORY_SCOPE_AGENT) < (unsigned)NB)
            __builtin_amdgcn_s_sleep(1);
        asm volatile("" ::: "memory");
    }
    __syncthreads();
}

__device__ __forceinline__ double agent_ld(const double* p) {
    return __hip_atomic_load(p, __ATOMIC_RELAXED, __HIP_MEMORY_SCOPE_AGENT);
}
__device__ __forceinline__ void agent_st(double* p, double v) {
    __hip_atomic_store(p, v, __ATOMIC_RELAXED, __HIP_MEMORY_SCOPE_AGENT);
}

// ---------------------------------------------------------------------------
// Fused kernel (round-5 structure; only the barrier ordering flavor changed).
//   Blocks [0,NB)      : tail path (16 blocks).
//   Blocks [NB, NB+NMV): streaming matvec partials.
// ---------------------------------------------------------------------------
__global__ __launch_bounds__(256) void k_fused(
    const float* __restrict__ x, const float* __restrict__ W,
    const int* __restrict__ eidx, const float* __restrict__ eattr,
    double* __restrict__ ws,
    const float* __restrict__ b1, const float* __restrict__ W2, const float* __restrict__ b2,
    const float* __restrict__ c1w, const float* __restrict__ c1b,
    const float* __restrict__ c2w, const float* __restrict__ c2b,
    const float* __restrict__ f1W, const float* __restrict__ f1b,
    const float* __restrict__ f2W, const float* __restrict__ f2b,
    const float* __restrict__ f3W, const float* __restrict__ f3b,
    float* __restrict__ out)
{
    const int b = blockIdx.x;
    const int tid = threadIdx.x;
    const int wave = tid >> 6, lane = tid & 63;

    // Persistent tail state: sxw[129] | sdinv[3*129] | sh1[3*129]
    __shared__ double P[129 + 387 + 387];
    // Time-aliased scratch (1935 doubles): hp[4][3][NN] during aggregation,
    // finale buffers afterwards (disjoint lifetimes).
    __shared__ double SCR[1935];
    __shared__ double ws4[4];                 // matvec wave partials
    __shared__ double fcb[38];                // fc1o[32] | fc2o[6]

    if (b >= NB) {
        // ---- Streaming matvec partial: one (row, chunk) dot-product block.
        // x non-temporal so the 135 MB stream doesn't evict W (L2-hot, 129x reuse).
        const int bm = b - NB;
        const int r = bm / CHUNKS, ch = bm % CHUNKS;
        const vfloat4* xp = (const vfloat4*)(x + (size_t)r * FF + (size_t)ch * CHUNK);
        const float4*  wp = (const float4*)(W + (size_t)ch * CHUNK);
        double acc0 = 0.0, acc1 = 0.0;
#pragma unroll
        for (int i = 0; i < CHUNK / (256 * 4); ++i) {   // 8 iters
            vfloat4 xv = __builtin_nontemporal_load(xp + tid + i * 256);
            float4  wv = wp[tid + i * 256];
            acc0 += (double)xv[0] * (double)wv.x + (double)xv[1] * (double)wv.y;
            acc1 += (double)xv[2] * (double)wv.z + (double)xv[3] * (double)wv.w;
        }
        double acc = acc0 + acc1;
        for (int off = 32; off > 0; off >>= 1) acc += __shfl_down(acc, off, 64);
        if (lane == 0) ws4[wave] = acc;
        __syncthreads();
        if (tid == 0) {
            const double v = (ws4[0] + ws4[1]) + (ws4[2] + ws4[3]);
            agent_st(&ws[OFF_PARTIAL + bm], v);
            asm volatile("s_waitcnt vmcnt(0)" ::: "memory");  // store before signal
            __hip_atomic_fetch_add(&g_sync[(bm & 63) * LSTRIDE], 1u,
                                   __ATOMIC_RELAXED, __HIP_MEMORY_SCOPE_AGENT);
        }
        return;
    }

    // ======================== tail path (b in [0,NB)) ========================
    double* sxw   = P;            // [NN]
    double* sdinv = P + 129;      // [3*NN]
    double* sh1   = P + 516;      // [3*NN]
    double (*hp)[3][NN] = (double(*)[3][NN])SCR;   // also dp (degree partials)

    // ---- Prefetch this block's edge records FIRST (cold-miss latency hides
    // under the LDS zeroing below and the concurrent matvec stream).
    int er[EPT], ec[EPT];
    float ea[EPT][3];
#pragma unroll
    for (int i = 0; i < EPT; ++i) {
        const int e = b * EPB + i * 256 + tid;
        er[i] = eidx[e];
        ec[i] = eidx[EE + e];
        ea[i][0] = eattr[e * 3 + 0];
        ea[i][1] = eattr[e * 3 + 1];
        ea[i][2] = eattr[e * 3 + 2];
    }

    // ---- Degree partials (overlaps matvec stream)
    for (int i = tid; i < 4 * 3 * NN; i += 256) ((double*)hp)[i] = 0.0;
    __syncthreads();
#pragma unroll
    for (int i = 0; i < EPT; ++i) {
        const int cl = ec[i];
#pragma unroll
        for (int c = 0; c < 3; ++c)
            unsafeAtomicAdd(&hp[wave][c][cl], (double)ea[i][c]);
    }
    __syncthreads();
    for (int i = tid; i < 3 * NN; i += 256) {
        const int c = i / NN, j = i % NN;
        agent_st(&ws[OFF_DEGP + b * (3 * NN) + i],
                 (hp[0][c][j] + hp[1][c][j]) + (hp[2][c][j] + hp[3][c][j]));
    }
    gbar(&g_sync[64 * LSTRIDE]);

    // ---- dinv (still overlapping matvec; agent loads of the 16 partials)
    for (int v = tid; v < 3 * NN; v += 256) {
        double d = 1.0;                                  // self loop weight
#pragma unroll
        for (int k = 0; k < NB; ++k) d += agent_ld(&ws[OFF_DEGP + k * (3 * NN) + v]);
        sdinv[v] = (d > 0.0) ? 1.0 / sqrt(d) : 0.0;
    }
    __syncthreads();

    // ---- Wait for all matvec partials: 64 lanes on 64 private cachelines.
    // 4128 = 64*64 + 32 -> lanes 0..31 expect 65, lanes 32..63 expect 64.
    if (tid < 64) {
        unsigned* c = &g_sync[tid * LSTRIDE];
        const unsigned expct = (tid < 32) ? 65u : 64u;
        while (__hip_atomic_load(c, __ATOMIC_RELAXED, __HIP_MEMORY_SCOPE_AGENT) < expct)
            __builtin_amdgcn_s_sleep(8);
    }
    __syncthreads();

    // ---- xw row sums (coherence-point reads)
    for (int j = tid; j < NN; j += 256) {
        double s = 0.0;
#pragma unroll
        for (int k = 0; k < CHUNKS; ++k)
            s += agent_ld(&ws[OFF_PARTIAL + j * CHUNKS + k]);
        sxw[j] = s;
    }
    for (int i = tid; i < 4 * 3 * NN; i += 256) ((double*)hp)[i] = 0.0;
    __syncthreads();

    // ---- Phase 1: layer-1 aggregation; norms cached in registers
    double enw[EPT][3];
#pragma unroll
    for (int i = 0; i < EPT; ++i) {
        const int r = er[i], cl = ec[i];
        const double xwr = sxw[r];
#pragma unroll
        for (int c = 0; c < 3; ++c) {
            const double nw = sdinv[c * NN + r] * (double)ea[i][c] * sdinv[c * NN + cl];
            enw[i][c] = nw;
            unsafeAtomicAdd(&hp[wave][c][cl], nw * xwr);
        }
    }
    __syncthreads();
    for (int i = tid; i < 3 * NN; i += 256) {
        const int c = i / NN, j = i % NN;
        agent_st(&ws[OFF_H1P + b * (3 * NN) + i],
                 (hp[0][c][j] + hp[1][c][j]) + (hp[2][c][j] + hp[3][c][j]));
    }
    gbar(&g_sync[65 * LSTRIDE]);

    // ---- Phase 2: h1 (redundant per block)
    const double bb1 = (double)b1[0];
    for (int i = tid; i < 3 * NN; i += 256) {
        const int j = i % NN;
        const double dv = sdinv[i];
        double s = dv * dv * sxw[j] + bb1;
#pragma unroll
        for (int k = 0; k < NB; ++k) s += agent_ld(&ws[OFF_H1P + k * (3 * NN) + i]);
        sh1[i] = s;
    }
    for (int i = tid; i < 4 * 3 * NN; i += 256) ((double*)hp)[i] = 0.0;
    __syncthreads();

    // ---- Phase 3: layer-2 aggregation (same edges; register-cached norms)
    const double w2 = (double)W2[0];
#pragma unroll
    for (int i = 0; i < EPT; ++i) {
        const int r = er[i], cl = ec[i];
#pragma unroll
        for (int c = 0; c < 3; ++c)
            unsafeAtomicAdd(&hp[wave][c][cl], enw[i][c] * (sh1[c * NN + r] * w2));
    }
    __syncthreads();
    for (int i = tid; i < 3 * NN; i += 256) {
        const int c = i / NN, j = i % NN;
        agent_st(&ws[OFF_H2P + b * (3 * NN) + i],
                 (hp[0][c][j] + hp[1][c][j]) + (hp[2][c][j] + hp[3][c][j]));
    }

    // ---- Final barrier: arrive-only for b!=0 (relaxed; __syncthreads above
    // drained all H2P stores to the coherence point).
    __syncthreads();
    if (b != 0) {
        if (tid == 0)
            __hip_atomic_fetch_add(&g_sync[66 * LSTRIDE], 1u,
                                   __ATOMIC_RELAXED, __HIP_MEMORY_SCOPE_AGENT);
        return;
    }
    if (tid == 0) {
        __hip_atomic_fetch_add(&g_sync[66 * LSTRIDE], 1u,
                               __ATOMIC_RELAXED, __HIP_MEMORY_SCOPE_AGENT);
        while (__hip_atomic_load(&g_sync[66 * LSTRIDE], __ATOMIC_RELAXED,
                                 __HIP_MEMORY_SCOPE_AGENT) < (unsigned)NB)
            __builtin_amdgcn_s_sleep(1);
        asm volatile("" ::: "memory");
    }
    __syncthreads();

    // ---- Finale: block 0 finishes the network
    double* z0   = SCR;                    // [3*NN]  live: z-fill .. conv1
    double* z1   = SCR + 387;              // [3*NN]  live: z-fill .. conv1
    int*    rnk  = (int*)(SCR + 774);      // [3*NN] ints, live: rank .. z-fill
    double* c1o  = SCR + 774;              // [3*3*127] live: conv1 .. conv2
    double* h2f  = SCR + 1548;             // [3*NN]  live: h2 .. z-fill
    double* c2o  = SCR;                    // [3*123] live: conv2 .. pool
    double* allx = SCR + 369;              // [363]   live: pool .. fc1
    double* fc1o = fcb;                    // [32]
    double* fc2o = fcb + 32;               // [6]

    const double bb2 = (double)b2[0];
    for (int i = tid; i < 3 * NN; i += 256) {
        const double dv = sdinv[i];
        double s = dv * dv * (sh1[i] * w2) + bb2;
#pragma unroll
        for (int k = 0; k < NB; ++k) s += agent_ld(&ws[OFF_H2P + k * (3 * NN) + i]);
        h2f[i] = s;
    }
    __syncthreads();

    // SortPool: stable argsort of -h2 (descending, ties by index), k = N
    for (int i = tid; i < 3 * NN; i += 256) {
        const int c = i / NN, j = i % NN;
        const double v = h2f[c * NN + j];
        int rk = 0;
        for (int q = 0; q < NN; ++q) {
            const double u = h2f[c * NN + q];
            rk += (u > v) || (u == v && q < j);
        }
        rnk[i] = rk;
    }
    __syncthreads();
    for (int i = tid; i < 3 * NN; i += 256) {
        const int c = i / NN;
        const int rk = rnk[i];
        z0[c * NN + rk] = sh1[i];
        z1[c * NN + rk] = h2f[i];
    }
    __syncthreads();

    // conv1 (in=2,out=3,k=3, VALID) -> 127   (rnk dead; c1o region free)
    for (int i = tid; i < 3 * 3 * 127; i += 256) {
        const int c = i / (3 * 127), rem = i % (3 * 127), o = rem / 127, p = rem % 127;
        double s = (double)c1b[o];
#pragma unroll
        for (int k = 0; k < 3; ++k) {
            s += (double)c1w[(o * 2 + 0) * 3 + k] * z0[c * NN + p + k];
            s += (double)c1w[(o * 2 + 1) * 3 + k] * z1[c * NN + p + k];
        }
        c1o[(c * 3 + o) * 127 + p] = s;
    }
    __syncthreads();

    // pool1 fused into conv2 (identical f64 op order to materialized version)
    for (int i = tid; i < 3 * 123; i += 256) {
        const int c = i / 123, p = i % 123;
        double s = (double)c2b[0];
#pragma unroll
        for (int ic = 0; ic < 3; ++ic)
#pragma unroll
            for (int k = 0; k < 3; ++k) {
                const double* base = c1o + (c * 3 + ic) * 127 + p + k;
                const double m = fmax(base[0], fmax(base[1], base[2]));
                s += (double)c2w[ic * 3 + k] * m;
            }
        c2o[c * 123 + p] = s;
    }
    __syncthreads();
    for (int i = tid; i < 3 * 121; i += 256) {
        const int c = i / 121, p = i % 121;
        allx[c * 121 + p] = fmax(c2o[c * 123 + p],
                            fmax(c2o[c * 123 + p + 1], c2o[c * 123 + p + 2]));
    }
    __syncthreads();

    // fc1: 363 -> 32, ELU (8 lanes per output, aligned subgroups)
    {
        const int j = tid >> 3, t = tid & 7;
        double s = 0.0;
        for (int i = t; i < 363; i += 8) s += allx[i] * (double)f1W[i * 32 + j];
        s += __shfl_down(s, 4, 8);
        s += __shfl_down(s, 2, 8);
        s += __shfl_down(s, 1, 8);
        if (t == 0) {
            s += (double)f1b[j];
            fc1o[j] = (s > 0.0) ? s : expm1(s);
        }
    }
    __syncthreads();
    if (tid < 6) {
        double s = (double)f2b[tid];
        for (int i = 0; i < 32; ++i) s += fc1o[i] * (double)f2W[i * 6 + tid];
        fc2o[tid] = (s > 0.0) ? s : expm1(s);
    }
    __syncthreads();
    if (tid < 2) {
        double s = (double)f3b[tid];
        for (int i = 0; i < 6; ++i) s += fc2o[i] * (double)f3W[i * 2 + tid];
        out[tid] = (float)s;
    }

    // ---- Self-reset sync counters for the next launch (block 0 is the only
    // remaining participant: it observed all 16 arrivals on line 66 and all
    // 4128 stream signals, so no other block can touch g_sync again).
    __syncthreads();
    if (tid < 67)
        __hip_atomic_store(&g_sync[tid * LSTRIDE], 0u,
                           __ATOMIC_RELAXED, __HIP_MEMORY_SCOPE_AGENT);
}

extern "C" void kernel_launch(void* const* d_in, const int* in_sizes, int n_in,
                              void* d_out, int out_size, void* d_ws, size_t ws_size,
                              hipStream_t stream) {
    const float* x    = (const float*)d_in[0];
    const int*   eidx = (const int*)d_in[1];
    const float* eattr= (const float*)d_in[2];
    const float* g1W  = (const float*)d_in[3];
    const float* g1b  = (const float*)d_in[4];
    const float* g2W  = (const float*)d_in[5];
    const float* g2b  = (const float*)d_in[6];
    const float* c1w  = (const float*)d_in[7];
    const float* c1b  = (const float*)d_in[8];
    const float* c2w  = (const float*)d_in[9];
    const float* c2b  = (const float*)d_in[10];
    const float* f1W  = (const float*)d_in[11];
    const float* f1b  = (const float*)d_in[12];
    const float* f2W  = (const float*)d_in[13];
    const float* f2b  = (const float*)d_in[14];
    const float* f3W  = (const float*)d_in[15];
    const float* f3b  = (const float*)d_in[16];
    float* out = (float*)d_out;
    double* ws = (double*)d_ws;

    // No memset: sync counters live in g_sync (zero at load, self-reset each run).
    k_fused<<<NMV + NB, 256, 0, stream>>>(
        x, g1W, eidx, eattr, ws,
        g1b, g2W, g2b, c1w, c1b, c2w, c2b,
        f1W, f1b, f2W, f2b, f3W, f3b, out);
}